// Round 21
// baseline (235.428 us; speedup 1.0000x reference)
//
#include <hip/hip_runtime.h>

#define NN 100000
#define NE 1600000

#define BNODES 256                          // nodes per sort bucket
#define NBUCK ((NN + BNODES - 1) / BNODES)  // 391
#define TILE 4096                           // edges per bin tile
#define NTILE ((NE + TILE - 1) / TILE)      // 391
#define CAP 5120                            // LDS sort capacity
#define HTILE 4096                          // edges per bucket_hist block
#define NHB ((NE + HTILE - 1) / HTILE)      // 391

#define RPB 16                              // rows per spmm block
#define ECAP 768                            // LDS edge cap (mean 256, ~32 sigma)

typedef unsigned long long u64;
typedef unsigned short ushort_t;
typedef __attribute__((ext_vector_type(8))) short bf16x8;
typedef __attribute__((ext_vector_type(4))) float f32x4;

// float -> bf16 RNE
__device__ __forceinline__ ushort_t f2bf(float f) {
    unsigned u = __float_as_uint(f);
    u += 0x7fffu + ((u >> 16) & 1u);
    return (ushort_t)(u >> 16);
}
__device__ __forceinline__ float bf2f(ushort_t b) {
    return __uint_as_float(((unsigned)b) << 16);
}

// ---------------- bucket histogram ----------------

__global__ __launch_bounds__(256) void bucket_hist(const int* __restrict__ dst,
                                                   int* __restrict__ gcnt) {
    __shared__ int cnt[NBUCK];
    int t = threadIdx.x;
    for (int b = t; b < NBUCK; b += 256) cnt[b] = 0;
    __syncthreads();
    int e0 = blockIdx.x * HTILE + t * 16;
    if (e0 < NE) {
#pragma unroll
        for (int q = 0; q < 4; ++q) {
            int4 d = *reinterpret_cast<const int4*>(dst + e0 + q * 4);
            atomicAdd(&cnt[d.x >> 8], 1);
            atomicAdd(&cnt[d.y >> 8], 1);
            atomicAdd(&cnt[d.z >> 8], 1);
            atomicAdd(&cnt[d.w >> 8], 1);
        }
    }
    __syncthreads();
    for (int b = t; b < NBUCK; b += 256)
        if (cnt[b]) atomicAdd(&gcnt[b], cnt[b]);
}

__global__ __launch_bounds__(512) void bucket_scan(const int* __restrict__ gcnt,
                                                   int* __restrict__ bbase,
                                                   int* __restrict__ wcur,
                                                   int* __restrict__ offsets) {
    __shared__ int tmp[512];
    int t = threadIdx.x;
    int v = (t < NBUCK) ? gcnt[t] : 0;
    tmp[t] = v;
    __syncthreads();
    for (int off = 1; off < 512; off <<= 1) {
        int u = (t >= off) ? tmp[t - off] : 0;
        __syncthreads();
        tmp[t] += u;
        __syncthreads();
    }
    if (t < NBUCK) {
        int base = tmp[t] - v;
        bbase[t] = base;
        wcur[t]  = base;
    }
    if (t == NBUCK - 1) bbase[NBUCK] = tmp[t];
    if (t == 0) offsets[NN] = NE;
}

// ---------------- phase A: bin edges into 391 buckets ----------------

__global__ __launch_bounds__(256) void bin_kernel(const int* __restrict__ src,
                                                  const int* __restrict__ dst,
                                                  const float* __restrict__ w,
                                                  int* __restrict__ wcur,
                                                  u64* __restrict__ rec) {
    __shared__ int cnt[512];
    __shared__ int base_l[512];
    __shared__ int gbase[NBUCK];
    __shared__ int lofs[NBUCK];
    __shared__ int scan2[256];
    __shared__ u64 stage[TILE];
    __shared__ unsigned short stage_b[TILE];

    int t = threadIdx.x;
    cnt[t] = 0;
    cnt[t + 256] = 0;
    for (int b = t; b < NBUCK; b += 256) lofs[b] = 0;   // strided: NBUCK > 256
    __syncthreads();

    int e0 = blockIdx.x * TILE + t * 16;
    bool valid = e0 < NE;
    int d[16], s[16];
    float ww[16];
    if (valid) {
#pragma unroll
        for (int q = 0; q < 4; ++q) {
            int4 dv = *reinterpret_cast<const int4*>(dst + e0 + q * 4);
            int4 sv = *reinterpret_cast<const int4*>(src + e0 + q * 4);
            float4 wv = *reinterpret_cast<const float4*>(w + e0 + q * 4);
            d[q * 4 + 0] = dv.x; d[q * 4 + 1] = dv.y; d[q * 4 + 2] = dv.z; d[q * 4 + 3] = dv.w;
            s[q * 4 + 0] = sv.x; s[q * 4 + 1] = sv.y; s[q * 4 + 2] = sv.z; s[q * 4 + 3] = sv.w;
            ww[q * 4 + 0] = wv.x; ww[q * 4 + 1] = wv.y; ww[q * 4 + 2] = wv.z; ww[q * 4 + 3] = wv.w;
        }
#pragma unroll
        for (int i = 0; i < 16; ++i) atomicAdd(&cnt[d[i] >> 8], 1);
    }
    __syncthreads();

    int pair = cnt[2 * t] + cnt[2 * t + 1];
    scan2[t] = pair;
    __syncthreads();
    for (int off = 1; off < 256; off <<= 1) {
        int u = (t >= off) ? scan2[t - off] : 0;
        __syncthreads();
        scan2[t] += u;
        __syncthreads();
    }
    int excl = scan2[t] - pair;
    base_l[2 * t]     = excl;
    base_l[2 * t + 1] = excl + cnt[2 * t];
    for (int b = t; b < NBUCK; b += 256)
        gbase[b] = atomicAdd(&wcur[b], cnt[b]);
    __syncthreads();

    if (valid) {
#pragma unroll
        for (int i = 0; i < 16; ++i) {
            int b = d[i] >> 8;
            int p = base_l[b] + atomicAdd(&lofs[b], 1);
            u64 hi = (u64)(unsigned)(s[i] | ((d[i] & 0xFF) << 17));
            stage[p]   = (hi << 32) | (u64)(unsigned)__float_as_int(ww[i]);
            stage_b[p] = (unsigned short)b;
        }
    }
    __syncthreads();

    int tot = scan2[255];
    for (int i = t; i < tot; i += 256) {
        int b = stage_b[i];
        rec[gbase[b] + (i - base_l[b])] = stage[i];
    }
}

// ---------------- phase B: per-bucket count+scan+rank -> offsets & CSR ------
// DETERMINISM: within-node order = sorted by 64-bit record value (ties are
// bitwise identical -> commute). Per-record rank-permute (R19-proven).

__global__ __launch_bounds__(256) void sort_kernel(const u64* __restrict__ rec,
                                                   const int* __restrict__ bbase,
                                                   int* __restrict__ offsets,
                                                   int2* __restrict__ csr) {
    __shared__ int2 outb[CAP];
    __shared__ unsigned short nodeof[CAP];
    __shared__ int scanb[BNODES];   // inclusive scan = segment END
    __shared__ int off_l[BNODES];   // segment BEGIN
    __shared__ int ctr[BNODES];

    int b = blockIdx.x;
    int node0 = b << 8;
    int t = threadIdx.x;
    int gbase = bbase[b];
    int gend  = bbase[b + 1];
    int cntb  = gend - gbase;

    ctr[t] = 0;
    __syncthreads();

    for (int i = t; i < cntb; i += 256) {
        u64 r = rec[gbase + i];
        int n = (int)((unsigned)(r >> 32) >> 17);
        atomicAdd(&ctr[n], 1);
    }
    __syncthreads();

    int v = ctr[t];
    scanb[t] = v;
    __syncthreads();
    for (int off = 1; off < 256; off <<= 1) {
        int u = (t >= off) ? scanb[t - off] : 0;
        __syncthreads();
        scanb[t] += u;
        __syncthreads();
    }
    int excl = scanb[t] - v;
    off_l[t] = excl;
    ctr[t] = 0;
    int node = node0 + t;
    if (node < NN) offsets[node] = gbase + excl;
    __syncthreads();

    if (cntb <= CAP) {
        for (int i = t; i < cntb; i += 256) {
            u64 r = rec[gbase + i];
            unsigned hi = (unsigned)(r >> 32);
            int n = (int)(hi >> 17);
            int slot = off_l[n] + atomicAdd(&ctr[n], 1);
            outb[slot]   = make_int2((int)(hi & 0x1FFFF), (int)(unsigned)r);
            nodeof[slot] = (unsigned short)n;
        }
        __syncthreads();

        for (int i = t; i < cntb; i += 256) {
            int2 ri = outb[i];
            u64 ki = ((u64)(unsigned)ri.x << 32) | (unsigned)ri.y;
            int n   = nodeof[i];
            int beg = off_l[n];
            int end = scanb[n];
            int rank = 0;
            for (int j = beg; j < end; ++j) {
                int2 rj = outb[j];
                u64 kj = ((u64)(unsigned)rj.x << 32) | (unsigned)rj.y;
                rank += (int)((kj < ki) | ((kj == ki) & (j < i)));
            }
            csr[gbase + beg + rank] = ri;
        }
    } else {
        for (int i = t; i < cntb; i += 256) {
            u64 r = rec[gbase + i];
            unsigned hi = (unsigned)(r >> 32);
            int n = (int)(hi >> 17);
            int slot = off_l[n] + atomicAdd(&ctr[n], 1);
            csr[gbase + slot] = make_int2((int)(hi & 0x1FFFF), (int)(unsigned)r);
        }
    }
}

// ---------------- W converter ----------------

__global__ __launch_bounds__(256) void wconv_kernel(const float* __restrict__ W1,
                                                    const float* __restrict__ W2,
                                                    const float* __restrict__ W3,
                                                    ushort_t* __restrict__ wt1,
                                                    ushort_t* __restrict__ wt2,
                                                    ushort_t* __restrict__ wt3) {
    int b = blockIdx.x;
    const float* W; ushort_t* wt; int K, bl;
    if (b < 8)       { W = W1; wt = wt1; K = 128; bl = b; }
    else if (b < 12) { W = W2; wt = wt2; K = 64;  bl = b - 8; }
    else             { W = W3; wt = wt3; K = 64;  bl = b - 12; }
    int u = (bl * 256 + threadIdx.x) * 4;
    if (u >= 64 * K) return;
    int c = u / K, k = u % K;
    ushort4 o;
    o.x = f2bf(W[(k + 0) * 64 + c]);
    o.y = f2bf(W[(k + 1) * 64 + c]);
    o.z = f2bf(W[(k + 2) * 64 + c]);
    o.w = f2bf(W[(k + 3) * 64 + c]);
    *reinterpret_cast<ushort4*>(wt + u) = o;
}

// ---------------- MFMA GEMM (layer 1 only) ----------------

template <int K, typename XT>
__global__ __launch_bounds__(256) void gemm_mfma(const XT* __restrict__ X,
                                                 const ushort_t* __restrict__ Wt,
                                                 ushort_t* __restrict__ S) {
    __shared__ ushort_t A_lds[64][K + 8];
    __shared__ ushort_t B_lds[64][K + 8];

    int t = threadIdx.x;

    for (int u = t; u < 64 * K / 8; u += 256) {
        int c = u / (K / 8), seg = u % (K / 8);
        bf16x8 v = *reinterpret_cast<const bf16x8*>(Wt + c * K + seg * 8);
        *reinterpret_cast<bf16x8*>(&B_lds[c][seg * 8]) = v;
    }

    int row_base = blockIdx.x * 64;
    if constexpr (sizeof(XT) == 4) {
        for (int u = t; u < 64 * K / 4; u += 256) {
            int r = u / (K / 4), seg = u % (K / 4);
            int g = min(row_base + r, NN - 1);
            float4 x = *reinterpret_cast<const float4*>((const float*)X + (size_t)g * K + seg * 4);
            unsigned p0 = (unsigned)f2bf(x.x) | ((unsigned)f2bf(x.y) << 16);
            unsigned p1 = (unsigned)f2bf(x.z) | ((unsigned)f2bf(x.w) << 16);
            *reinterpret_cast<uint2*>(&A_lds[r][seg * 4]) = make_uint2(p0, p1);
        }
    } else {
        for (int u = t; u < 64 * K / 8; u += 256) {
            int r = u / (K / 8), seg = u % (K / 8);
            int g = min(row_base + r, NN - 1);
            bf16x8 v = *reinterpret_cast<const bf16x8*>((const ushort_t*)X + (size_t)g * K + seg * 8);
            *reinterpret_cast<bf16x8*>(&A_lds[r][seg * 8]) = v;
        }
    }
    __syncthreads();

    int wave = t >> 6;
    int lane = t & 63;
    int grp  = lane >> 4;
    int lr   = lane & 15;
    int arow = wave * 16 + lr;

    f32x4 acc0 = {0.f, 0.f, 0.f, 0.f};
    f32x4 acc1 = {0.f, 0.f, 0.f, 0.f};
    f32x4 acc2 = {0.f, 0.f, 0.f, 0.f};
    f32x4 acc3 = {0.f, 0.f, 0.f, 0.f};

#pragma unroll
    for (int kc = 0; kc < K / 32; ++kc) {
        int ko = kc * 32 + grp * 8;
        bf16x8 a  = *reinterpret_cast<const bf16x8*>(&A_lds[arow][ko]);
        bf16x8 b0 = *reinterpret_cast<const bf16x8*>(&B_lds[lr][ko]);
        bf16x8 b1 = *reinterpret_cast<const bf16x8*>(&B_lds[16 + lr][ko]);
        bf16x8 b2 = *reinterpret_cast<const bf16x8*>(&B_lds[32 + lr][ko]);
        bf16x8 b3 = *reinterpret_cast<const bf16x8*>(&B_lds[48 + lr][ko]);
        acc0 = __builtin_amdgcn_mfma_f32_16x16x32_bf16(a, b0, acc0, 0, 0, 0);
        acc1 = __builtin_amdgcn_mfma_f32_16x16x32_bf16(a, b1, acc1, 0, 0, 0);
        acc2 = __builtin_amdgcn_mfma_f32_16x16x32_bf16(a, b2, acc2, 0, 0, 0);
        acc3 = __builtin_amdgcn_mfma_f32_16x16x32_bf16(a, b3, acc3, 0, 0, 0);
    }

#pragma unroll
    for (int r = 0; r < 4; ++r) {
        int orow = wave * 16 + grp * 4 + r;
        A_lds[orow][lr]      = f2bf(acc0[r]);
        A_lds[orow][16 + lr] = f2bf(acc1[r]);
        A_lds[orow][32 + lr] = f2bf(acc2[r]);
        A_lds[orow][48 + lr] = f2bf(acc3[r]);
    }
#pragma unroll
    for (int u = lane; u < 16 * 8; u += 64) {
        int r = u >> 3, sg = u & 7;
        int grow = row_base + wave * 16 + r;
        if (grow < NN) {
            bf16x8 v = *reinterpret_cast<const bf16x8*>(&A_lds[wave * 16 + r][sg * 8]);
            *reinterpret_cast<bf16x8*>(S + ((size_t)grow << 6) + sg * 8) = v;
        }
    }
}

// ---------------- SPMM gather (+ optionally FUSED next-layer GEMM) ----------
// 8 edges per VMEM instruction (R15). Rounds software-pipelined to DEPTH 2
// (R20's loop was depth-1: next round's gathers waited on this round's fmaf;
// named A/B buffers keep everything register-resident, rule #20).

#define SPMM_LOAD(Cw, Vv, RD)                                              \
    _Pragma("unroll") for (int r = 0; r < 4; ++r) {                        \
        int ei = eb[r] + (RD) * 8 + g;                                     \
        bool ok = ei < ee[r];                                              \
        int2 c = ecsr[ok ? ei : 0];                                        \
        Cw[r] = ok ? __int_as_float(c.y) : 0.f;                            \
        Vv[r] = *reinterpret_cast<const uint4*>(S + ((size_t)c.x << 6) + cl); \
    }

#define SPMM_CONS(Cw, Vv)                                                  \
    _Pragma("unroll") for (int r = 0; r < 4; ++r) {                        \
        acc[r][0] = fmaf(Cw[r], __uint_as_float(Vv[r].x << 16),          acc[r][0]); \
        acc[r][1] = fmaf(Cw[r], __uint_as_float(Vv[r].x & 0xffff0000u),  acc[r][1]); \
        acc[r][2] = fmaf(Cw[r], __uint_as_float(Vv[r].y << 16),          acc[r][2]); \
        acc[r][3] = fmaf(Cw[r], __uint_as_float(Vv[r].y & 0xffff0000u),  acc[r][3]); \
        acc[r][4] = fmaf(Cw[r], __uint_as_float(Vv[r].z << 16),          acc[r][4]); \
        acc[r][5] = fmaf(Cw[r], __uint_as_float(Vv[r].z & 0xffff0000u),  acc[r][5]); \
        acc[r][6] = fmaf(Cw[r], __uint_as_float(Vv[r].w << 16),          acc[r][6]); \
        acc[r][7] = fmaf(Cw[r], __uint_as_float(Vv[r].w & 0xffff0000u),  acc[r][7]); \
    }

template <bool RELU, bool FUSE, typename OT>
__global__ __launch_bounds__(256) void spmm_kernel(const int2* __restrict__ csr,
                                                   const int* __restrict__ offsets,
                                                   const ushort_t* __restrict__ S,
                                                   const float* __restrict__ bias,
                                                   OT* __restrict__ out,
                                                   const ushort_t* __restrict__ Wt,
                                                   ushort_t* __restrict__ Snext) {
    extern __shared__ char smem[];
    int2*     ecsr = (int2*)smem;                                   // ECAP*8
    int*      soff = (int*)(smem + ECAP * sizeof(int2));            // (RPB+1)*4
    ushort_t* ht   = (ushort_t*)(smem + ECAP * sizeof(int2) + 128); // 16*72*2 (FUSE)
    ushort_t* w2l  = ht + 16 * 72;                                  // 64*72*2 (FUSE)

    int t = threadIdx.x;
    int row_base = blockIdx.x * RPB;                  // NN % RPB == 0
    if (t <= RPB) soff[t] = offsets[row_base + t];

    if constexpr (FUSE) {                             // stage W (64x64 bf16)
        for (int i = t; i < 64 * 8; i += 256) {
            int rr = i >> 3, sg = i & 7;
            *reinterpret_cast<bf16x8*>(&w2l[rr * 72 + sg * 8]) =
                *reinterpret_cast<const bf16x8*>(Wt + rr * 64 + sg * 8);
        }
    }
    __syncthreads();
    int sbeg = soff[0];
    int cnt  = soff[RPB] - sbeg;
    bool fits = cnt <= ECAP;
    if (fits) {
        for (int i = t; i < cnt; i += 256) ecsr[i] = csr[sbeg + i];   // coalesced
    }
    __syncthreads();

    int wave = t >> 6;
    int lane = t & 63;
    int g    = lane >> 3;        // edge slot within round (0..7)
    int cl   = (lane & 7) * 8;   // this lane's 8 columns
    int r0   = wave * 4;

    int eb[4], ee[4];
#pragma unroll
    for (int r = 0; r < 4; ++r) {
        eb[r] = soff[r0 + r] - sbeg;
        ee[r] = soff[r0 + r + 1] - sbeg;
    }

    float acc[4][8] = {{0.f}};

    if (cnt > 0) {
        int rounds = 0;
#pragma unroll
        for (int r = 0; r < 4; ++r) rounds = max(rounds, (ee[r] - eb[r] + 7) >> 3);

        if (fits) {
            // depth-2 software pipeline: issue round rd+1's gathers before
            // consuming round rd (8 gathers in flight per wave, was 4)
            float wA[4], wB[4];
            uint4 vA[4], vB[4];
            int rd = 0;
            SPMM_LOAD(wA, vA, 0)
            while (rd < rounds) {
                if (rd + 1 < rounds) SPMM_LOAD(wB, vB, rd + 1)
                SPMM_CONS(wA, vA)
                ++rd;
                if (rd >= rounds) break;
                if (rd + 1 < rounds) SPMM_LOAD(wA, vA, rd + 1)
                SPMM_CONS(wB, vB)
                ++rd;
            }
        } else {
            for (int rd = 0; rd < rounds; ++rd) {
#pragma unroll
                for (int r = 0; r < 4; ++r) {
                    int ei = eb[r] + rd * 8 + g;
                    bool ok = ei < ee[r];
                    int2 c = csr[sbeg + (ok ? ei : 0)];
                    float wt = ok ? __int_as_float(c.y) : 0.f;
                    uint4 sv = *reinterpret_cast<const uint4*>(S + ((size_t)c.x << 6) + cl);
                    acc[r][0] = fmaf(wt, __uint_as_float(sv.x << 16), acc[r][0]);
                    acc[r][1] = fmaf(wt, __uint_as_float(sv.x & 0xffff0000u), acc[r][1]);
                    acc[r][2] = fmaf(wt, __uint_as_float(sv.y << 16), acc[r][2]);
                    acc[r][3] = fmaf(wt, __uint_as_float(sv.y & 0xffff0000u), acc[r][3]);
                    acc[r][4] = fmaf(wt, __uint_as_float(sv.z << 16), acc[r][4]);
                    acc[r][5] = fmaf(wt, __uint_as_float(sv.z & 0xffff0000u), acc[r][5]);
                    acc[r][6] = fmaf(wt, __uint_as_float(sv.w << 16), acc[r][6]);
                    acc[r][7] = fmaf(wt, __uint_as_float(sv.w & 0xffff0000u), acc[r][7]);
                }
            }
        }
    }

    // reduce the 8 edge-slots (lane bits 3,4,5)
#pragma unroll
    for (int r = 0; r < 4; ++r)
#pragma unroll
        for (int j = 0; j < 8; ++j) {
            acc[r][j] += __shfl_xor(acc[r][j], 8);
            acc[r][j] += __shfl_xor(acc[r][j], 16);
            acc[r][j] += __shfl_xor(acc[r][j], 32);
        }

    if (lane < 8) {
        float4 bv0 = *reinterpret_cast<const float4*>(bias + cl);
        float4 bv1 = *reinterpret_cast<const float4*>(bias + cl + 4);
#pragma unroll
        for (int r = 0; r < 4; ++r) {
            float o0 = acc[r][0] + bv0.x, o1 = acc[r][1] + bv0.y;
            float o2 = acc[r][2] + bv0.z, o3 = acc[r][3] + bv0.w;
            float o4 = acc[r][4] + bv1.x, o5 = acc[r][5] + bv1.y;
            float o6 = acc[r][6] + bv1.z, o7 = acc[r][7] + bv1.w;
            if (RELU) {
                o0 = fmaxf(o0, 0.f); o1 = fmaxf(o1, 0.f);
                o2 = fmaxf(o2, 0.f); o3 = fmaxf(o3, 0.f);
                o4 = fmaxf(o4, 0.f); o5 = fmaxf(o5, 0.f);
                o6 = fmaxf(o6, 0.f); o7 = fmaxf(o7, 0.f);
            }
            if constexpr (FUSE) {
                union { bf16x8 v; ushort_t u[8]; } hv;
                hv.u[0] = f2bf(o0); hv.u[1] = f2bf(o1); hv.u[2] = f2bf(o2); hv.u[3] = f2bf(o3);
                hv.u[4] = f2bf(o4); hv.u[5] = f2bf(o5); hv.u[6] = f2bf(o6); hv.u[7] = f2bf(o7);
                *reinterpret_cast<bf16x8*>(&ht[(r0 + r) * 72 + cl]) = hv.v;
            } else {
                size_t base = ((size_t)(row_base + r0 + r) << 6) + cl;
                if constexpr (sizeof(OT) == 2) {
                    ushort4 p0, p1;
                    p0.x = f2bf(o0); p0.y = f2bf(o1); p0.z = f2bf(o2); p0.w = f2bf(o3);
                    p1.x = f2bf(o4); p1.y = f2bf(o5); p1.z = f2bf(o6); p1.w = f2bf(o7);
                    *reinterpret_cast<ushort4*>((ushort_t*)out + base)     = p0;
                    *reinterpret_cast<ushort4*>((ushort_t*)out + base + 4) = p1;
                } else {
                    *reinterpret_cast<float4*>((float*)out + base)     = make_float4(o0, o1, o2, o3);
                    *reinterpret_cast<float4*>((float*)out + base + 4) = make_float4(o4, o5, o6, o7);
                }
            }
        }
    }

    if constexpr (FUSE) {
        __syncthreads();   // all 16 ht rows visible to all waves
        int grp = lane >> 4;   // 0..3
        int lr  = lane & 15;   // 0..15
        f32x4 aq = {0.f, 0.f, 0.f, 0.f};
#pragma unroll
        for (int kc = 0; kc < 2; ++kc) {
            int ko = kc * 32 + grp * 8;
            bf16x8 a = *reinterpret_cast<const bf16x8*>(&ht[lr * 72 + ko]);
            bf16x8 b = *reinterpret_cast<const bf16x8*>(&w2l[(wave * 16 + lr) * 72 + ko]);
            aq = __builtin_amdgcn_mfma_f32_16x16x32_bf16(a, b, aq, 0, 0, 0);
        }
#pragma unroll
        for (int r = 0; r < 4; ++r)
            Snext[((size_t)(row_base + grp * 4 + r) << 6) + wave * 16 + lr] = f2bf(aq[r]);
    }
}

// ---------------- launch ----------------

extern "C" void kernel_launch(void* const* d_in, const int* in_sizes, int n_in,
                              void* d_out, int out_size, void* d_ws, size_t ws_size,
                              hipStream_t stream) {
    const float* features = (const float*)d_in[0];
    const int*   src      = (const int*)d_in[1];
    const int*   dst      = (const int*)d_in[2];
    const float* ew       = (const float*)d_in[3];
    const float* W1       = (const float*)d_in[4];
    const float* b1       = (const float*)d_in[5];
    const float* W2       = (const float*)d_in[6];
    const float* b2       = (const float*)d_in[7];
    const float* W3       = (const float*)d_in[8];
    const float* b3       = (const float*)d_in[9];
    float*       out      = (float*)d_out;

    float*    s_f32  = (float*)d_ws;          // region A: S1, later S3
    ushort_t* sA_bf  = (ushort_t*)d_ws;
    float*    h_f32  = s_f32 + (size_t)NN * 64;  // region B: rec during build, S2 after
    ushort_t* sB_bf  = (ushort_t*)h_f32;
    int*   offsets = (int*)(h_f32 + (size_t)NN * 64);
    int*   gcnt    = offsets + NN + 4;
    int*   bbase   = gcnt + 512;
    int*   wcur    = bbase + 512;
    ushort_t* wt1  = (ushort_t*)(wcur + 512);
    ushort_t* wt2  = wt1 + 64 * 128;
    ushort_t* wt3  = wt2 + 64 * 64;
    int2*  csr     = (int2*)(wt3 + 64 * 64);
    u64*   rec     = (u64*)h_f32;             // dead before spmm1

    (void)hipMemsetAsync(gcnt, 0, NBUCK * sizeof(int), stream);
    wconv_kernel<<<16, 256, 0, stream>>>(W1, W2, W3, wt1, wt2, wt3);
    bucket_hist<<<NHB, 256, 0, stream>>>(dst, gcnt);
    bucket_scan<<<1, 512, 0, stream>>>(gcnt, bbase, wcur, offsets);
    bin_kernel<<<NTILE, 256, 0, stream>>>(src, dst, ew, wcur, rec);
    sort_kernel<<<NBUCK, 256, 0, stream>>>(rec, bbase, offsets, csr);

    int grid_gemm = (NN + 63) / 64;     // 1563
    int grid_spmm = NN / RPB;           // 6250
    size_t shm_plain = ECAP * 8 + 128;
    size_t shm_fused = shm_plain + (16 * 72 + 64 * 72) * 2;

    gemm_mfma<128, float><<<grid_gemm, 256, 0, stream>>>(features, wt1, sA_bf);
    spmm_kernel<true, true, ushort_t><<<grid_spmm, 256, shm_fused, stream>>>(
        csr, offsets, sA_bf, b1, (ushort_t*)nullptr, wt2, sB_bf);
    spmm_kernel<true, true, ushort_t><<<grid_spmm, 256, shm_fused, stream>>>(
        csr, offsets, sB_bf, b2, (ushort_t*)nullptr, wt3, sA_bf);
    spmm_kernel<false, false, float><<<grid_spmm, 256, shm_plain, stream>>>(
        csr, offsets, sA_bf, b3, out, (const ushort_t*)nullptr, (ushort_t*)nullptr);
}

// Round 22
// 228.861 us; speedup vs baseline: 1.0287x; 1.0287x over previous
//
#include <hip/hip_runtime.h>

#define NN 100000
#define NE 1600000

#define BNODES 256                          // nodes per sort bucket
#define NBUCK ((NN + BNODES - 1) / BNODES)  // 391
#define TILE 4096                           // edges per bin tile
#define NTILE ((NE + TILE - 1) / TILE)      // 391
#define CAP 5120                            // LDS sort capacity
#define HTILE 4096                          // edges per bucket_hist block
#define NHB ((NE + HTILE - 1) / HTILE)      // 391

#define RPB 16                              // rows per spmm block
#define ECAP 768                            // LDS edge cap (mean 256, ~32 sigma)

typedef unsigned long long u64;
typedef unsigned short ushort_t;
typedef __attribute__((ext_vector_type(8))) short bf16x8;
typedef __attribute__((ext_vector_type(4))) float f32x4;

// float -> bf16 RNE
__device__ __forceinline__ ushort_t f2bf(float f) {
    unsigned u = __float_as_uint(f);
    u += 0x7fffu + ((u >> 16) & 1u);
    return (ushort_t)(u >> 16);
}
__device__ __forceinline__ float bf2f(ushort_t b) {
    return __uint_as_float(((unsigned)b) << 16);
}

// ---------------- bucket histogram ----------------

__global__ __launch_bounds__(256) void bucket_hist(const int* __restrict__ dst,
                                                   int* __restrict__ gcnt) {
    __shared__ int cnt[NBUCK];
    int t = threadIdx.x;
    for (int b = t; b < NBUCK; b += 256) cnt[b] = 0;
    __syncthreads();
    int e0 = blockIdx.x * HTILE + t * 16;
    if (e0 < NE) {
#pragma unroll
        for (int q = 0; q < 4; ++q) {
            int4 d = *reinterpret_cast<const int4*>(dst + e0 + q * 4);
            atomicAdd(&cnt[d.x >> 8], 1);
            atomicAdd(&cnt[d.y >> 8], 1);
            atomicAdd(&cnt[d.z >> 8], 1);
            atomicAdd(&cnt[d.w >> 8], 1);
        }
    }
    __syncthreads();
    for (int b = t; b < NBUCK; b += 256)
        if (cnt[b]) atomicAdd(&gcnt[b], cnt[b]);
}

__global__ __launch_bounds__(512) void bucket_scan(const int* __restrict__ gcnt,
                                                   int* __restrict__ bbase,
                                                   int* __restrict__ wcur,
                                                   int* __restrict__ offsets) {
    __shared__ int tmp[512];
    int t = threadIdx.x;
    int v = (t < NBUCK) ? gcnt[t] : 0;
    tmp[t] = v;
    __syncthreads();
    for (int off = 1; off < 512; off <<= 1) {
        int u = (t >= off) ? tmp[t - off] : 0;
        __syncthreads();
        tmp[t] += u;
        __syncthreads();
    }
    if (t < NBUCK) {
        int base = tmp[t] - v;
        bbase[t] = base;
        wcur[t]  = base;
    }
    if (t == NBUCK - 1) bbase[NBUCK] = tmp[t];
    if (t == 0) offsets[NN] = NE;
}

// ---------------- phase A: bin edges into 391 buckets ----------------

__global__ __launch_bounds__(256) void bin_kernel(const int* __restrict__ src,
                                                  const int* __restrict__ dst,
                                                  const float* __restrict__ w,
                                                  int* __restrict__ wcur,
                                                  u64* __restrict__ rec) {
    __shared__ int cnt[512];
    __shared__ int base_l[512];
    __shared__ int gbase[NBUCK];
    __shared__ int lofs[NBUCK];
    __shared__ int scan2[256];
    __shared__ u64 stage[TILE];
    __shared__ unsigned short stage_b[TILE];

    int t = threadIdx.x;
    cnt[t] = 0;
    cnt[t + 256] = 0;
    for (int b = t; b < NBUCK; b += 256) lofs[b] = 0;   // strided: NBUCK > 256
    __syncthreads();

    int e0 = blockIdx.x * TILE + t * 16;
    bool valid = e0 < NE;
    int d[16], s[16];
    float ww[16];
    if (valid) {
#pragma unroll
        for (int q = 0; q < 4; ++q) {
            int4 dv = *reinterpret_cast<const int4*>(dst + e0 + q * 4);
            int4 sv = *reinterpret_cast<const int4*>(src + e0 + q * 4);
            float4 wv = *reinterpret_cast<const float4*>(w + e0 + q * 4);
            d[q * 4 + 0] = dv.x; d[q * 4 + 1] = dv.y; d[q * 4 + 2] = dv.z; d[q * 4 + 3] = dv.w;
            s[q * 4 + 0] = sv.x; s[q * 4 + 1] = sv.y; s[q * 4 + 2] = sv.z; s[q * 4 + 3] = sv.w;
            ww[q * 4 + 0] = wv.x; ww[q * 4 + 1] = wv.y; ww[q * 4 + 2] = wv.z; ww[q * 4 + 3] = wv.w;
        }
#pragma unroll
        for (int i = 0; i < 16; ++i) atomicAdd(&cnt[d[i] >> 8], 1);
    }
    __syncthreads();

    int pair = cnt[2 * t] + cnt[2 * t + 1];
    scan2[t] = pair;
    __syncthreads();
    for (int off = 1; off < 256; off <<= 1) {
        int u = (t >= off) ? scan2[t - off] : 0;
        __syncthreads();
        scan2[t] += u;
        __syncthreads();
    }
    int excl = scan2[t] - pair;
    base_l[2 * t]     = excl;
    base_l[2 * t + 1] = excl + cnt[2 * t];
    for (int b = t; b < NBUCK; b += 256)
        gbase[b] = atomicAdd(&wcur[b], cnt[b]);
    __syncthreads();

    if (valid) {
#pragma unroll
        for (int i = 0; i < 16; ++i) {
            int b = d[i] >> 8;
            int p = base_l[b] + atomicAdd(&lofs[b], 1);
            u64 hi = (u64)(unsigned)(s[i] | ((d[i] & 0xFF) << 17));
            stage[p]   = (hi << 32) | (u64)(unsigned)__float_as_int(ww[i]);
            stage_b[p] = (unsigned short)b;
        }
    }
    __syncthreads();

    int tot = scan2[255];
    for (int i = t; i < tot; i += 256) {
        int b = stage_b[i];
        rec[gbase[b] + (i - base_l[b])] = stage[i];
    }
}

// ---------------- phase B: per-bucket count+scan+rank -> offsets & CSR ------
// DETERMINISM: within-node order = sorted by 64-bit record value (ties are
// bitwise identical -> commute). Per-record rank-permute (R19-proven).

__global__ __launch_bounds__(256) void sort_kernel(const u64* __restrict__ rec,
                                                   const int* __restrict__ bbase,
                                                   int* __restrict__ offsets,
                                                   int2* __restrict__ csr) {
    __shared__ int2 outb[CAP];
    __shared__ unsigned short nodeof[CAP];
    __shared__ int scanb[BNODES];   // inclusive scan = segment END
    __shared__ int off_l[BNODES];   // segment BEGIN
    __shared__ int ctr[BNODES];

    int b = blockIdx.x;
    int node0 = b << 8;
    int t = threadIdx.x;
    int gbase = bbase[b];
    int gend  = bbase[b + 1];
    int cntb  = gend - gbase;

    ctr[t] = 0;
    __syncthreads();

    for (int i = t; i < cntb; i += 256) {
        u64 r = rec[gbase + i];
        int n = (int)((unsigned)(r >> 32) >> 17);
        atomicAdd(&ctr[n], 1);
    }
    __syncthreads();

    int v = ctr[t];
    scanb[t] = v;
    __syncthreads();
    for (int off = 1; off < 256; off <<= 1) {
        int u = (t >= off) ? scanb[t - off] : 0;
        __syncthreads();
        scanb[t] += u;
        __syncthreads();
    }
    int excl = scanb[t] - v;
    off_l[t] = excl;
    ctr[t] = 0;
    int node = node0 + t;
    if (node < NN) offsets[node] = gbase + excl;
    __syncthreads();

    if (cntb <= CAP) {
        for (int i = t; i < cntb; i += 256) {
            u64 r = rec[gbase + i];
            unsigned hi = (unsigned)(r >> 32);
            int n = (int)(hi >> 17);
            int slot = off_l[n] + atomicAdd(&ctr[n], 1);
            outb[slot]   = make_int2((int)(hi & 0x1FFFF), (int)(unsigned)r);
            nodeof[slot] = (unsigned short)n;
        }
        __syncthreads();

        for (int i = t; i < cntb; i += 256) {
            int2 ri = outb[i];
            u64 ki = ((u64)(unsigned)ri.x << 32) | (unsigned)ri.y;
            int n   = nodeof[i];
            int beg = off_l[n];
            int end = scanb[n];
            int rank = 0;
            for (int j = beg; j < end; ++j) {
                int2 rj = outb[j];
                u64 kj = ((u64)(unsigned)rj.x << 32) | (unsigned)rj.y;
                rank += (int)((kj < ki) | ((kj == ki) & (j < i)));
            }
            csr[gbase + beg + rank] = ri;
        }
    } else {
        for (int i = t; i < cntb; i += 256) {
            u64 r = rec[gbase + i];
            unsigned hi = (unsigned)(r >> 32);
            int n = (int)(hi >> 17);
            int slot = off_l[n] + atomicAdd(&ctr[n], 1);
            csr[gbase + slot] = make_int2((int)(hi & 0x1FFFF), (int)(unsigned)r);
        }
    }
}

// ---------------- W converter ----------------

__global__ __launch_bounds__(256) void wconv_kernel(const float* __restrict__ W1,
                                                    const float* __restrict__ W2,
                                                    const float* __restrict__ W3,
                                                    ushort_t* __restrict__ wt1,
                                                    ushort_t* __restrict__ wt2,
                                                    ushort_t* __restrict__ wt3) {
    int b = blockIdx.x;
    const float* W; ushort_t* wt; int K, bl;
    if (b < 8)       { W = W1; wt = wt1; K = 128; bl = b; }
    else if (b < 12) { W = W2; wt = wt2; K = 64;  bl = b - 8; }
    else             { W = W3; wt = wt3; K = 64;  bl = b - 12; }
    int u = (bl * 256 + threadIdx.x) * 4;
    if (u >= 64 * K) return;
    int c = u / K, k = u % K;
    ushort4 o;
    o.x = f2bf(W[(k + 0) * 64 + c]);
    o.y = f2bf(W[(k + 1) * 64 + c]);
    o.z = f2bf(W[(k + 2) * 64 + c]);
    o.w = f2bf(W[(k + 3) * 64 + c]);
    *reinterpret_cast<ushort4*>(wt + u) = o;
}

// ---------------- MFMA GEMM (layer 1 only) ----------------

template <int K, typename XT>
__global__ __launch_bounds__(256) void gemm_mfma(const XT* __restrict__ X,
                                                 const ushort_t* __restrict__ Wt,
                                                 ushort_t* __restrict__ S) {
    __shared__ ushort_t A_lds[64][K + 8];
    __shared__ ushort_t B_lds[64][K + 8];

    int t = threadIdx.x;

    for (int u = t; u < 64 * K / 8; u += 256) {
        int c = u / (K / 8), seg = u % (K / 8);
        bf16x8 v = *reinterpret_cast<const bf16x8*>(Wt + c * K + seg * 8);
        *reinterpret_cast<bf16x8*>(&B_lds[c][seg * 8]) = v;
    }

    int row_base = blockIdx.x * 64;
    if constexpr (sizeof(XT) == 4) {
        for (int u = t; u < 64 * K / 4; u += 256) {
            int r = u / (K / 4), seg = u % (K / 4);
            int g = min(row_base + r, NN - 1);
            float4 x = *reinterpret_cast<const float4*>((const float*)X + (size_t)g * K + seg * 4);
            unsigned p0 = (unsigned)f2bf(x.x) | ((unsigned)f2bf(x.y) << 16);
            unsigned p1 = (unsigned)f2bf(x.z) | ((unsigned)f2bf(x.w) << 16);
            *reinterpret_cast<uint2*>(&A_lds[r][seg * 4]) = make_uint2(p0, p1);
        }
    } else {
        for (int u = t; u < 64 * K / 8; u += 256) {
            int r = u / (K / 8), seg = u % (K / 8);
            int g = min(row_base + r, NN - 1);
            bf16x8 v = *reinterpret_cast<const bf16x8*>((const ushort_t*)X + (size_t)g * K + seg * 8);
            *reinterpret_cast<bf16x8*>(&A_lds[r][seg * 8]) = v;
        }
    }
    __syncthreads();

    int wave = t >> 6;
    int lane = t & 63;
    int grp  = lane >> 4;
    int lr   = lane & 15;
    int arow = wave * 16 + lr;

    f32x4 acc0 = {0.f, 0.f, 0.f, 0.f};
    f32x4 acc1 = {0.f, 0.f, 0.f, 0.f};
    f32x4 acc2 = {0.f, 0.f, 0.f, 0.f};
    f32x4 acc3 = {0.f, 0.f, 0.f, 0.f};

#pragma unroll
    for (int kc = 0; kc < K / 32; ++kc) {
        int ko = kc * 32 + grp * 8;
        bf16x8 a  = *reinterpret_cast<const bf16x8*>(&A_lds[arow][ko]);
        bf16x8 b0 = *reinterpret_cast<const bf16x8*>(&B_lds[lr][ko]);
        bf16x8 b1 = *reinterpret_cast<const bf16x8*>(&B_lds[16 + lr][ko]);
        bf16x8 b2 = *reinterpret_cast<const bf16x8*>(&B_lds[32 + lr][ko]);
        bf16x8 b3 = *reinterpret_cast<const bf16x8*>(&B_lds[48 + lr][ko]);
        acc0 = __builtin_amdgcn_mfma_f32_16x16x32_bf16(a, b0, acc0, 0, 0, 0);
        acc1 = __builtin_amdgcn_mfma_f32_16x16x32_bf16(a, b1, acc1, 0, 0, 0);
        acc2 = __builtin_amdgcn_mfma_f32_16x16x32_bf16(a, b2, acc2, 0, 0, 0);
        acc3 = __builtin_amdgcn_mfma_f32_16x16x32_bf16(a, b3, acc3, 0, 0, 0);
    }

#pragma unroll
    for (int r = 0; r < 4; ++r) {
        int orow = wave * 16 + grp * 4 + r;
        A_lds[orow][lr]      = f2bf(acc0[r]);
        A_lds[orow][16 + lr] = f2bf(acc1[r]);
        A_lds[orow][32 + lr] = f2bf(acc2[r]);
        A_lds[orow][48 + lr] = f2bf(acc3[r]);
    }
#pragma unroll
    for (int u = lane; u < 16 * 8; u += 64) {
        int r = u >> 3, sg = u & 7;
        int grow = row_base + wave * 16 + r;
        if (grow < NN) {
            bf16x8 v = *reinterpret_cast<const bf16x8*>(&A_lds[wave * 16 + r][sg * 8]);
            *reinterpret_cast<bf16x8*>(S + ((size_t)grow << 6) + sg * 8) = v;
        }
    }
}

// ---------------- SPMM gather (+ optionally FUSED next-layer GEMM) ----------
// 8 edges per VMEM instruction (R15-proven, depth-1: R14/R21 showed deeper
// per-wave pipelines trade occupancy 1:1 and don't help -- the binding
// resource is L3 random 64B-line service, ~3.8 TB/s measured).

template <bool RELU, bool FUSE, typename OT>
__global__ __launch_bounds__(256) void spmm_kernel(const int2* __restrict__ csr,
                                                   const int* __restrict__ offsets,
                                                   const ushort_t* __restrict__ S,
                                                   const float* __restrict__ bias,
                                                   OT* __restrict__ out,
                                                   const ushort_t* __restrict__ Wt,
                                                   ushort_t* __restrict__ Snext) {
    extern __shared__ char smem[];
    int2*     ecsr = (int2*)smem;                                   // ECAP*8
    int*      soff = (int*)(smem + ECAP * sizeof(int2));            // (RPB+1)*4
    ushort_t* ht   = (ushort_t*)(smem + ECAP * sizeof(int2) + 128); // 16*72*2 (FUSE)
    ushort_t* w2l  = ht + 16 * 72;                                  // 64*72*2 (FUSE)

    int t = threadIdx.x;
    int row_base = blockIdx.x * RPB;                  // NN % RPB == 0
    if (t <= RPB) soff[t] = offsets[row_base + t];

    if constexpr (FUSE) {                             // stage W (64x64 bf16)
        for (int i = t; i < 64 * 8; i += 256) {
            int rr = i >> 3, sg = i & 7;
            *reinterpret_cast<bf16x8*>(&w2l[rr * 72 + sg * 8]) =
                *reinterpret_cast<const bf16x8*>(Wt + rr * 64 + sg * 8);
        }
    }
    __syncthreads();
    int sbeg = soff[0];
    int cnt  = soff[RPB] - sbeg;
    bool fits = cnt <= ECAP;
    if (fits) {
        for (int i = t; i < cnt; i += 256) ecsr[i] = csr[sbeg + i];   // coalesced
    }
    __syncthreads();

    int wave = t >> 6;
    int lane = t & 63;
    int g    = lane >> 3;        // edge slot within round (0..7)
    int cl   = (lane & 7) * 8;   // this lane's 8 columns
    int r0   = wave * 4;

    int eb[4], ee[4];
#pragma unroll
    for (int r = 0; r < 4; ++r) {
        eb[r] = soff[r0 + r] - sbeg;
        ee[r] = soff[r0 + r + 1] - sbeg;
    }

    float acc[4][8] = {{0.f}};

    if (cnt > 0) {
        int rounds = 0;
#pragma unroll
        for (int r = 0; r < 4; ++r) rounds = max(rounds, (ee[r] - eb[r] + 7) >> 3);

        if (fits) {
            for (int rd = 0; rd < rounds; ++rd) {
#pragma unroll
                for (int r = 0; r < 4; ++r) {
                    int ei = eb[r] + rd * 8 + g;
                    bool ok = ei < ee[r];
                    int2 c = ecsr[ok ? ei : 0];
                    float wt = ok ? __int_as_float(c.y) : 0.f;
                    uint4 sv = *reinterpret_cast<const uint4*>(S + ((size_t)c.x << 6) + cl);
                    acc[r][0] = fmaf(wt, __uint_as_float(sv.x << 16), acc[r][0]);
                    acc[r][1] = fmaf(wt, __uint_as_float(sv.x & 0xffff0000u), acc[r][1]);
                    acc[r][2] = fmaf(wt, __uint_as_float(sv.y << 16), acc[r][2]);
                    acc[r][3] = fmaf(wt, __uint_as_float(sv.y & 0xffff0000u), acc[r][3]);
                    acc[r][4] = fmaf(wt, __uint_as_float(sv.z << 16), acc[r][4]);
                    acc[r][5] = fmaf(wt, __uint_as_float(sv.z & 0xffff0000u), acc[r][5]);
                    acc[r][6] = fmaf(wt, __uint_as_float(sv.w << 16), acc[r][6]);
                    acc[r][7] = fmaf(wt, __uint_as_float(sv.w & 0xffff0000u), acc[r][7]);
                }
            }
        } else {
            for (int rd = 0; rd < rounds; ++rd) {
#pragma unroll
                for (int r = 0; r < 4; ++r) {
                    int ei = eb[r] + rd * 8 + g;
                    bool ok = ei < ee[r];
                    int2 c = csr[sbeg + (ok ? ei : 0)];
                    float wt = ok ? __int_as_float(c.y) : 0.f;
                    uint4 sv = *reinterpret_cast<const uint4*>(S + ((size_t)c.x << 6) + cl);
                    acc[r][0] = fmaf(wt, __uint_as_float(sv.x << 16), acc[r][0]);
                    acc[r][1] = fmaf(wt, __uint_as_float(sv.x & 0xffff0000u), acc[r][1]);
                    acc[r][2] = fmaf(wt, __uint_as_float(sv.y << 16), acc[r][2]);
                    acc[r][3] = fmaf(wt, __uint_as_float(sv.y & 0xffff0000u), acc[r][3]);
                    acc[r][4] = fmaf(wt, __uint_as_float(sv.z << 16), acc[r][4]);
                    acc[r][5] = fmaf(wt, __uint_as_float(sv.z & 0xffff0000u), acc[r][5]);
                    acc[r][6] = fmaf(wt, __uint_as_float(sv.w << 16), acc[r][6]);
                    acc[r][7] = fmaf(wt, __uint_as_float(sv.w & 0xffff0000u), acc[r][7]);
                }
            }
        }
    }

    // reduce the 8 edge-slots (lane bits 3,4,5)
#pragma unroll
    for (int r = 0; r < 4; ++r)
#pragma unroll
        for (int j = 0; j < 8; ++j) {
            acc[r][j] += __shfl_xor(acc[r][j], 8);
            acc[r][j] += __shfl_xor(acc[r][j], 16);
            acc[r][j] += __shfl_xor(acc[r][j], 32);
        }

    if (lane < 8) {
        float4 bv0 = *reinterpret_cast<const float4*>(bias + cl);
        float4 bv1 = *reinterpret_cast<const float4*>(bias + cl + 4);
#pragma unroll
        for (int r = 0; r < 4; ++r) {
            float o0 = acc[r][0] + bv0.x, o1 = acc[r][1] + bv0.y;
            float o2 = acc[r][2] + bv0.z, o3 = acc[r][3] + bv0.w;
            float o4 = acc[r][4] + bv1.x, o5 = acc[r][5] + bv1.y;
            float o6 = acc[r][6] + bv1.z, o7 = acc[r][7] + bv1.w;
            if (RELU) {
                o0 = fmaxf(o0, 0.f); o1 = fmaxf(o1, 0.f);
                o2 = fmaxf(o2, 0.f); o3 = fmaxf(o3, 0.f);
                o4 = fmaxf(o4, 0.f); o5 = fmaxf(o5, 0.f);
                o6 = fmaxf(o6, 0.f); o7 = fmaxf(o7, 0.f);
            }
            if constexpr (FUSE) {
                union { bf16x8 v; ushort_t u[8]; } hv;
                hv.u[0] = f2bf(o0); hv.u[1] = f2bf(o1); hv.u[2] = f2bf(o2); hv.u[3] = f2bf(o3);
                hv.u[4] = f2bf(o4); hv.u[5] = f2bf(o5); hv.u[6] = f2bf(o6); hv.u[7] = f2bf(o7);
                *reinterpret_cast<bf16x8*>(&ht[(r0 + r) * 72 + cl]) = hv.v;
            } else {
                size_t base = ((size_t)(row_base + r0 + r) << 6) + cl;
                if constexpr (sizeof(OT) == 2) {
                    ushort4 p0, p1;
                    p0.x = f2bf(o0); p0.y = f2bf(o1); p0.z = f2bf(o2); p0.w = f2bf(o3);
                    p1.x = f2bf(o4); p1.y = f2bf(o5); p1.z = f2bf(o6); p1.w = f2bf(o7);
                    *reinterpret_cast<ushort4*>((ushort_t*)out + base)     = p0;
                    *reinterpret_cast<ushort4*>((ushort_t*)out + base + 4) = p1;
                } else {
                    *reinterpret_cast<float4*>((float*)out + base)     = make_float4(o0, o1, o2, o3);
                    *reinterpret_cast<float4*>((float*)out + base + 4) = make_float4(o4, o5, o6, o7);
                }
            }
        }
    }

    if constexpr (FUSE) {
        __syncthreads();   // all 16 ht rows visible to all waves
        int grp = lane >> 4;   // 0..3
        int lr  = lane & 15;   // 0..15
        f32x4 aq = {0.f, 0.f, 0.f, 0.f};
#pragma unroll
        for (int kc = 0; kc < 2; ++kc) {
            int ko = kc * 32 + grp * 8;
            bf16x8 a = *reinterpret_cast<const bf16x8*>(&ht[lr * 72 + ko]);
            bf16x8 b = *reinterpret_cast<const bf16x8*>(&w2l[(wave * 16 + lr) * 72 + ko]);
            aq = __builtin_amdgcn_mfma_f32_16x16x32_bf16(a, b, aq, 0, 0, 0);
        }
#pragma unroll
        for (int r = 0; r < 4; ++r)
            Snext[((size_t)(row_base + grp * 4 + r) << 6) + wave * 16 + lr] = f2bf(aq[r]);
    }
}

// ---------------- launch ----------------

extern "C" void kernel_launch(void* const* d_in, const int* in_sizes, int n_in,
                              void* d_out, int out_size, void* d_ws, size_t ws_size,
                              hipStream_t stream) {
    const float* features = (const float*)d_in[0];
    const int*   src      = (const int*)d_in[1];
    const int*   dst      = (const int*)d_in[2];
    const float* ew       = (const float*)d_in[3];
    const float* W1       = (const float*)d_in[4];
    const float* b1       = (const float*)d_in[5];
    const float* W2       = (const float*)d_in[6];
    const float* b2       = (const float*)d_in[7];
    const float* W3       = (const float*)d_in[8];
    const float* b3       = (const float*)d_in[9];
    float*       out      = (float*)d_out;

    float*    s_f32  = (float*)d_ws;          // region A: S1, later S3
    ushort_t* sA_bf  = (ushort_t*)d_ws;
    float*    h_f32  = s_f32 + (size_t)NN * 64;  // region B: rec during build, S2 after
    ushort_t* sB_bf  = (ushort_t*)h_f32;
    int*   offsets = (int*)(h_f32 + (size_t)NN * 64);
    int*   gcnt    = offsets + NN + 4;
    int*   bbase   = gcnt + 512;
    int*   wcur    = bbase + 512;
    ushort_t* wt1  = (ushort_t*)(wcur + 512);
    ushort_t* wt2  = wt1 + 64 * 128;
    ushort_t* wt3  = wt2 + 64 * 64;
    int2*  csr     = (int2*)(wt3 + 64 * 64);
    u64*   rec     = (u64*)h_f32;             // dead before spmm1

    (void)hipMemsetAsync(gcnt, 0, NBUCK * sizeof(int), stream);
    wconv_kernel<<<16, 256, 0, stream>>>(W1, W2, W3, wt1, wt2, wt3);
    bucket_hist<<<NHB, 256, 0, stream>>>(dst, gcnt);
    bucket_scan<<<1, 512, 0, stream>>>(gcnt, bbase, wcur, offsets);
    bin_kernel<<<NTILE, 256, 0, stream>>>(src, dst, ew, wcur, rec);
    sort_kernel<<<NBUCK, 256, 0, stream>>>(rec, bbase, offsets, csr);

    int grid_gemm = (NN + 63) / 64;     // 1563
    int grid_spmm = NN / RPB;           // 6250
    size_t shm_plain = ECAP * 8 + 128;
    size_t shm_fused = shm_plain + (16 * 72 + 64 * 72) * 2;

    gemm_mfma<128, float><<<grid_gemm, 256, 0, stream>>>(features, wt1, sA_bf);
    spmm_kernel<true, true, ushort_t><<<grid_spmm, 256, shm_fused, stream>>>(
        csr, offsets, sA_bf, b1, (ushort_t*)nullptr, wt2, sB_bf);
    spmm_kernel<true, true, ushort_t><<<grid_spmm, 256, shm_fused, stream>>>(
        csr, offsets, sB_bf, b2, (ushort_t*)nullptr, wt3, sA_bf);
    spmm_kernel<false, false, float><<<grid_spmm, 256, shm_plain, stream>>>(
        csr, offsets, sA_bf, b3, out, (const ushort_t*)nullptr, (ushort_t*)nullptr);
}

// Round 23
// 198.667 us; speedup vs baseline: 1.1850x; 1.1520x over previous
//
#include <hip/hip_runtime.h>

#define NN 100000
#define NE 1600000

#define BNODES 256                          // nodes per sort bucket
#define NBUCK ((NN + BNODES - 1) / BNODES)  // 391
#define TILE 4096                           // edges per bin tile
#define NTILE ((NE + TILE - 1) / TILE)      // 391
#define CAP 5120                            // LDS sort capacity
#define HTILE 4096                          // edges per bucket_hist block
#define NHB ((NE + HTILE - 1) / HTILE)      // 391

#define RPB 16                              // rows per spmm block
#define ECAP 768                            // LDS edge cap (mean 256, ~32 sigma)

typedef unsigned long long u64;
typedef unsigned short ushort_t;
typedef __attribute__((ext_vector_type(8))) short bf16x8;
typedef __attribute__((ext_vector_type(4))) float f32x4;

// float -> bf16 RNE
__device__ __forceinline__ ushort_t f2bf(float f) {
    unsigned u = __float_as_uint(f);
    u += 0x7fffu + ((u >> 16) & 1u);
    return (ushort_t)(u >> 16);
}
__device__ __forceinline__ float bf2f(ushort_t b) {
    return __uint_as_float(((unsigned)b) << 16);
}

// ---------------- bucket histogram ----------------

__global__ __launch_bounds__(256) void bucket_hist(const int* __restrict__ dst,
                                                   int* __restrict__ gcnt) {
    __shared__ int cnt[NBUCK];
    int t = threadIdx.x;
    for (int b = t; b < NBUCK; b += 256) cnt[b] = 0;
    __syncthreads();
    int e0 = blockIdx.x * HTILE + t * 16;
    if (e0 < NE) {
#pragma unroll
        for (int q = 0; q < 4; ++q) {
            int4 d = *reinterpret_cast<const int4*>(dst + e0 + q * 4);
            atomicAdd(&cnt[d.x >> 8], 1);
            atomicAdd(&cnt[d.y >> 8], 1);
            atomicAdd(&cnt[d.z >> 8], 1);
            atomicAdd(&cnt[d.w >> 8], 1);
        }
    }
    __syncthreads();
    for (int b = t; b < NBUCK; b += 256)
        if (cnt[b]) atomicAdd(&gcnt[b], cnt[b]);
}

__global__ __launch_bounds__(512) void bucket_scan(const int* __restrict__ gcnt,
                                                   int* __restrict__ bbase,
                                                   int* __restrict__ wcur,
                                                   int* __restrict__ offsets) {
    __shared__ int tmp[512];
    int t = threadIdx.x;
    int v = (t < NBUCK) ? gcnt[t] : 0;
    tmp[t] = v;
    __syncthreads();
    for (int off = 1; off < 512; off <<= 1) {
        int u = (t >= off) ? tmp[t - off] : 0;
        __syncthreads();
        tmp[t] += u;
        __syncthreads();
    }
    if (t < NBUCK) {
        int base = tmp[t] - v;
        bbase[t] = base;
        wcur[t]  = base;
    }
    if (t == NBUCK - 1) bbase[NBUCK] = tmp[t];
    if (t == 0) offsets[NN] = NE;
}

// ---------------- phase A: bin edges into 391 buckets ----------------

__global__ __launch_bounds__(256) void bin_kernel(const int* __restrict__ src,
                                                  const int* __restrict__ dst,
                                                  const float* __restrict__ w,
                                                  int* __restrict__ wcur,
                                                  u64* __restrict__ rec) {
    __shared__ int cnt[512];
    __shared__ int base_l[512];
    __shared__ int gbase[NBUCK];
    __shared__ int lofs[NBUCK];
    __shared__ int scan2[256];
    __shared__ u64 stage[TILE];
    __shared__ unsigned short stage_b[TILE];

    int t = threadIdx.x;
    cnt[t] = 0;
    cnt[t + 256] = 0;
    for (int b = t; b < NBUCK; b += 256) lofs[b] = 0;   // strided: NBUCK > 256
    __syncthreads();

    int e0 = blockIdx.x * TILE + t * 16;
    bool valid = e0 < NE;
    int d[16], s[16];
    float ww[16];
    if (valid) {
#pragma unroll
        for (int q = 0; q < 4; ++q) {
            int4 dv = *reinterpret_cast<const int4*>(dst + e0 + q * 4);
            int4 sv = *reinterpret_cast<const int4*>(src + e0 + q * 4);
            float4 wv = *reinterpret_cast<const float4*>(w + e0 + q * 4);
            d[q * 4 + 0] = dv.x; d[q * 4 + 1] = dv.y; d[q * 4 + 2] = dv.z; d[q * 4 + 3] = dv.w;
            s[q * 4 + 0] = sv.x; s[q * 4 + 1] = sv.y; s[q * 4 + 2] = sv.z; s[q * 4 + 3] = sv.w;
            ww[q * 4 + 0] = wv.x; ww[q * 4 + 1] = wv.y; ww[q * 4 + 2] = wv.z; ww[q * 4 + 3] = wv.w;
        }
#pragma unroll
        for (int i = 0; i < 16; ++i) atomicAdd(&cnt[d[i] >> 8], 1);
    }
    __syncthreads();

    int pair = cnt[2 * t] + cnt[2 * t + 1];
    scan2[t] = pair;
    __syncthreads();
    for (int off = 1; off < 256; off <<= 1) {
        int u = (t >= off) ? scan2[t - off] : 0;
        __syncthreads();
        scan2[t] += u;
        __syncthreads();
    }
    int excl = scan2[t] - pair;
    base_l[2 * t]     = excl;
    base_l[2 * t + 1] = excl + cnt[2 * t];
    for (int b = t; b < NBUCK; b += 256)
        gbase[b] = atomicAdd(&wcur[b], cnt[b]);
    __syncthreads();

    if (valid) {
#pragma unroll
        for (int i = 0; i < 16; ++i) {
            int b = d[i] >> 8;
            int p = base_l[b] + atomicAdd(&lofs[b], 1);
            u64 hi = (u64)(unsigned)(s[i] | ((d[i] & 0xFF) << 17));
            stage[p]   = (hi << 32) | (u64)(unsigned)__float_as_int(ww[i]);
            stage_b[p] = (unsigned short)b;
        }
    }
    __syncthreads();

    int tot = scan2[255];
    for (int i = t; i < tot; i += 256) {
        int b = stage_b[i];
        rec[gbase[b] + (i - base_l[b])] = stage[i];
    }
}

// ---------------- phase B: per-bucket count+scan+rank -> offsets & CSR ------
// DETERMINISM: within-node order = sorted by 64-bit record value (ties are
// bitwise identical -> commute). Per-record rank-permute (R19-proven).

__global__ __launch_bounds__(256) void sort_kernel(const u64* __restrict__ rec,
                                                   const int* __restrict__ bbase,
                                                   int* __restrict__ offsets,
                                                   int2* __restrict__ csr) {
    __shared__ int2 outb[CAP];
    __shared__ unsigned short nodeof[CAP];
    __shared__ int scanb[BNODES];   // inclusive scan = segment END
    __shared__ int off_l[BNODES];   // segment BEGIN
    __shared__ int ctr[BNODES];

    int b = blockIdx.x;
    int node0 = b << 8;
    int t = threadIdx.x;
    int gbase = bbase[b];
    int gend  = bbase[b + 1];
    int cntb  = gend - gbase;

    ctr[t] = 0;
    __syncthreads();

    for (int i = t; i < cntb; i += 256) {
        u64 r = rec[gbase + i];
        int n = (int)((unsigned)(r >> 32) >> 17);
        atomicAdd(&ctr[n], 1);
    }
    __syncthreads();

    int v = ctr[t];
    scanb[t] = v;
    __syncthreads();
    for (int off = 1; off < 256; off <<= 1) {
        int u = (t >= off) ? scanb[t - off] : 0;
        __syncthreads();
        scanb[t] += u;
        __syncthreads();
    }
    int excl = scanb[t] - v;
    off_l[t] = excl;
    ctr[t] = 0;
    int node = node0 + t;
    if (node < NN) offsets[node] = gbase + excl;
    __syncthreads();

    if (cntb <= CAP) {
        for (int i = t; i < cntb; i += 256) {
            u64 r = rec[gbase + i];
            unsigned hi = (unsigned)(r >> 32);
            int n = (int)(hi >> 17);
            int slot = off_l[n] + atomicAdd(&ctr[n], 1);
            outb[slot]   = make_int2((int)(hi & 0x1FFFF), (int)(unsigned)r);
            nodeof[slot] = (unsigned short)n;
        }
        __syncthreads();

        for (int i = t; i < cntb; i += 256) {
            int2 ri = outb[i];
            u64 ki = ((u64)(unsigned)ri.x << 32) | (unsigned)ri.y;
            int n   = nodeof[i];
            int beg = off_l[n];
            int end = scanb[n];
            int rank = 0;
            for (int j = beg; j < end; ++j) {
                int2 rj = outb[j];
                u64 kj = ((u64)(unsigned)rj.x << 32) | (unsigned)rj.y;
                rank += (int)((kj < ki) | ((kj == ki) & (j < i)));
            }
            csr[gbase + beg + rank] = ri;
        }
    } else {
        for (int i = t; i < cntb; i += 256) {
            u64 r = rec[gbase + i];
            unsigned hi = (unsigned)(r >> 32);
            int n = (int)(hi >> 17);
            int slot = off_l[n] + atomicAdd(&ctr[n], 1);
            csr[gbase + slot] = make_int2((int)(hi & 0x1FFFF), (int)(unsigned)r);
        }
    }
}

// ---------------- W converter ----------------

__global__ __launch_bounds__(256) void wconv_kernel(const float* __restrict__ W1,
                                                    const float* __restrict__ W2,
                                                    const float* __restrict__ W3,
                                                    ushort_t* __restrict__ wt1,
                                                    ushort_t* __restrict__ wt2,
                                                    ushort_t* __restrict__ wt3) {
    int b = blockIdx.x;
    const float* W; ushort_t* wt; int K, bl;
    if (b < 8)       { W = W1; wt = wt1; K = 128; bl = b; }
    else if (b < 12) { W = W2; wt = wt2; K = 64;  bl = b - 8; }
    else             { W = W3; wt = wt3; K = 64;  bl = b - 12; }
    int u = (bl * 256 + threadIdx.x) * 4;
    if (u >= 64 * K) return;
    int c = u / K, k = u % K;
    ushort4 o;
    o.x = f2bf(W[(k + 0) * 64 + c]);
    o.y = f2bf(W[(k + 1) * 64 + c]);
    o.z = f2bf(W[(k + 2) * 64 + c]);
    o.w = f2bf(W[(k + 3) * 64 + c]);
    *reinterpret_cast<ushort4*>(wt + u) = o;
}

// ---------------- MFMA GEMM (layer 1 only) ----------------

template <int K, typename XT>
__global__ __launch_bounds__(256) void gemm_mfma(const XT* __restrict__ X,
                                                 const ushort_t* __restrict__ Wt,
                                                 ushort_t* __restrict__ S) {
    __shared__ ushort_t A_lds[64][K + 8];
    __shared__ ushort_t B_lds[64][K + 8];

    int t = threadIdx.x;

    for (int u = t; u < 64 * K / 8; u += 256) {
        int c = u / (K / 8), seg = u % (K / 8);
        bf16x8 v = *reinterpret_cast<const bf16x8*>(Wt + c * K + seg * 8);
        *reinterpret_cast<bf16x8*>(&B_lds[c][seg * 8]) = v;
    }

    int row_base = blockIdx.x * 64;
    if constexpr (sizeof(XT) == 4) {
        for (int u = t; u < 64 * K / 4; u += 256) {
            int r = u / (K / 4), seg = u % (K / 4);
            int g = min(row_base + r, NN - 1);
            float4 x = *reinterpret_cast<const float4*>((const float*)X + (size_t)g * K + seg * 4);
            unsigned p0 = (unsigned)f2bf(x.x) | ((unsigned)f2bf(x.y) << 16);
            unsigned p1 = (unsigned)f2bf(x.z) | ((unsigned)f2bf(x.w) << 16);
            *reinterpret_cast<uint2*>(&A_lds[r][seg * 4]) = make_uint2(p0, p1);
        }
    } else {
        for (int u = t; u < 64 * K / 8; u += 256) {
            int r = u / (K / 8), seg = u % (K / 8);
            int g = min(row_base + r, NN - 1);
            bf16x8 v = *reinterpret_cast<const bf16x8*>((const ushort_t*)X + (size_t)g * K + seg * 8);
            *reinterpret_cast<bf16x8*>(&A_lds[r][seg * 8]) = v;
        }
    }
    __syncthreads();

    int wave = t >> 6;
    int lane = t & 63;
    int grp  = lane >> 4;
    int lr   = lane & 15;
    int arow = wave * 16 + lr;

    f32x4 acc0 = {0.f, 0.f, 0.f, 0.f};
    f32x4 acc1 = {0.f, 0.f, 0.f, 0.f};
    f32x4 acc2 = {0.f, 0.f, 0.f, 0.f};
    f32x4 acc3 = {0.f, 0.f, 0.f, 0.f};

#pragma unroll
    for (int kc = 0; kc < K / 32; ++kc) {
        int ko = kc * 32 + grp * 8;
        bf16x8 a  = *reinterpret_cast<const bf16x8*>(&A_lds[arow][ko]);
        bf16x8 b0 = *reinterpret_cast<const bf16x8*>(&B_lds[lr][ko]);
        bf16x8 b1 = *reinterpret_cast<const bf16x8*>(&B_lds[16 + lr][ko]);
        bf16x8 b2 = *reinterpret_cast<const bf16x8*>(&B_lds[32 + lr][ko]);
        bf16x8 b3 = *reinterpret_cast<const bf16x8*>(&B_lds[48 + lr][ko]);
        acc0 = __builtin_amdgcn_mfma_f32_16x16x32_bf16(a, b0, acc0, 0, 0, 0);
        acc1 = __builtin_amdgcn_mfma_f32_16x16x32_bf16(a, b1, acc1, 0, 0, 0);
        acc2 = __builtin_amdgcn_mfma_f32_16x16x32_bf16(a, b2, acc2, 0, 0, 0);
        acc3 = __builtin_amdgcn_mfma_f32_16x16x32_bf16(a, b3, acc3, 0, 0, 0);
    }

#pragma unroll
    for (int r = 0; r < 4; ++r) {
        int orow = wave * 16 + grp * 4 + r;
        A_lds[orow][lr]      = f2bf(acc0[r]);
        A_lds[orow][16 + lr] = f2bf(acc1[r]);
        A_lds[orow][32 + lr] = f2bf(acc2[r]);
        A_lds[orow][48 + lr] = f2bf(acc3[r]);
    }
#pragma unroll
    for (int u = lane; u < 16 * 8; u += 64) {
        int r = u >> 3, sg = u & 7;
        int grow = row_base + wave * 16 + r;
        if (grow < NN) {
            bf16x8 v = *reinterpret_cast<const bf16x8*>(&A_lds[wave * 16 + r][sg * 8]);
            *reinterpret_cast<bf16x8*>(S + ((size_t)grow << 6) + sg * 8) = v;
        }
    }
}

// ---------------- SPMM gather (+ optionally FUSED next-layer GEMM) ----------
// 4 edges per VMEM instruction (R15's pattern: 16 lanes/row x 8B uint2).
// R19-R22 A/B evidence: the 8-edge (16B/lane) variant regressed spmm ~30%
// (48.5-53.5us vs R15's <40) -- likely TA distinct-line serialization (16
// lines/instr vs 8). Reverting the gather core; sort determinism + fusion
// kept.

template <bool RELU, bool FUSE, typename OT>
__global__ __launch_bounds__(256) void spmm_kernel(const int2* __restrict__ csr,
                                                   const int* __restrict__ offsets,
                                                   const ushort_t* __restrict__ S,
                                                   const float* __restrict__ bias,
                                                   OT* __restrict__ out,
                                                   const ushort_t* __restrict__ Wt,
                                                   ushort_t* __restrict__ Snext) {
    extern __shared__ char smem[];
    int2*     ecsr = (int2*)smem;                                   // ECAP*8
    int*      soff = (int*)(smem + ECAP * sizeof(int2));            // (RPB+1)*4
    ushort_t* ht   = (ushort_t*)(smem + ECAP * sizeof(int2) + 128); // 16*72*2 (FUSE)
    ushort_t* w2l  = ht + 16 * 72;                                  // 64*72*2 (FUSE)

    int t = threadIdx.x;
    int row_base = blockIdx.x * RPB;                  // NN % RPB == 0
    if (t <= RPB) soff[t] = offsets[row_base + t];

    if constexpr (FUSE) {                             // stage W (64x64 bf16)
        for (int i = t; i < 64 * 8; i += 256) {
            int rr = i >> 3, sg = i & 7;
            *reinterpret_cast<bf16x8*>(&w2l[rr * 72 + sg * 8]) =
                *reinterpret_cast<const bf16x8*>(Wt + rr * 64 + sg * 8);
        }
    }
    __syncthreads();
    int sbeg = soff[0];
    int cnt  = soff[RPB] - sbeg;
    bool fits = cnt <= ECAP;
    if (fits) {
        for (int i = t; i < cnt; i += 256) ecsr[i] = csr[sbeg + i];   // coalesced
    }
    __syncthreads();

    int wave = t >> 6;
    int lane = t & 63;
    int g    = lane >> 4;        // edge slot within round (0..3)
    int cl   = (lane & 15) * 4;  // this lane's 4 columns
    int r0   = wave * 4;

    int eb[4], ee[4];
#pragma unroll
    for (int r = 0; r < 4; ++r) {
        eb[r] = soff[r0 + r] - sbeg;
        ee[r] = soff[r0 + r + 1] - sbeg;
    }

    float acc[4][4] = {{0.f}};

    if (cnt > 0) {
        int rounds = 0;
#pragma unroll
        for (int r = 0; r < 4; ++r) rounds = max(rounds, (ee[r] - eb[r] + 3) >> 2);

        if (fits) {
            for (int rd = 0; rd < rounds; ++rd) {
#pragma unroll
                for (int r = 0; r < 4; ++r) {
                    int ei = eb[r] + rd * 4 + g;
                    bool ok = ei < ee[r];
                    int2 c = ecsr[ok ? ei : 0];
                    float wt = ok ? __int_as_float(c.y) : 0.f;
                    uint2 sv = *reinterpret_cast<const uint2*>(S + ((size_t)c.x << 6) + cl);
                    acc[r][0] = fmaf(wt, __uint_as_float(sv.x << 16), acc[r][0]);
                    acc[r][1] = fmaf(wt, __uint_as_float(sv.x & 0xffff0000u), acc[r][1]);
                    acc[r][2] = fmaf(wt, __uint_as_float(sv.y << 16), acc[r][2]);
                    acc[r][3] = fmaf(wt, __uint_as_float(sv.y & 0xffff0000u), acc[r][3]);
                }
            }
        } else {
            for (int rd = 0; rd < rounds; ++rd) {
#pragma unroll
                for (int r = 0; r < 4; ++r) {
                    int ei = eb[r] + rd * 4 + g;
                    bool ok = ei < ee[r];
                    int2 c = csr[sbeg + (ok ? ei : 0)];
                    float wt = ok ? __int_as_float(c.y) : 0.f;
                    uint2 sv = *reinterpret_cast<const uint2*>(S + ((size_t)c.x << 6) + cl);
                    acc[r][0] = fmaf(wt, __uint_as_float(sv.x << 16), acc[r][0]);
                    acc[r][1] = fmaf(wt, __uint_as_float(sv.x & 0xffff0000u), acc[r][1]);
                    acc[r][2] = fmaf(wt, __uint_as_float(sv.y << 16), acc[r][2]);
                    acc[r][3] = fmaf(wt, __uint_as_float(sv.y & 0xffff0000u), acc[r][3]);
                }
            }
        }
    }

    // reduce the 4 edge-slots (lane bits 4,5)
#pragma unroll
    for (int r = 0; r < 4; ++r)
#pragma unroll
        for (int j = 0; j < 4; ++j) {
            acc[r][j] += __shfl_xor(acc[r][j], 16);
            acc[r][j] += __shfl_xor(acc[r][j], 32);
        }

    if (lane < 16) {
        float4 bv = *reinterpret_cast<const float4*>(bias + cl);
#pragma unroll
        for (int r = 0; r < 4; ++r) {
            float o0 = acc[r][0] + bv.x, o1 = acc[r][1] + bv.y;
            float o2 = acc[r][2] + bv.z, o3 = acc[r][3] + bv.w;
            if (RELU) {
                o0 = fmaxf(o0, 0.f); o1 = fmaxf(o1, 0.f);
                o2 = fmaxf(o2, 0.f); o3 = fmaxf(o3, 0.f);
            }
            if constexpr (FUSE) {
                // stage relu'd bf16 h chunk (row r0+r, cols cl..cl+3) in LDS
                ushort4 hv;
                hv.x = f2bf(o0); hv.y = f2bf(o1); hv.z = f2bf(o2); hv.w = f2bf(o3);
                *reinterpret_cast<ushort4*>(&ht[(r0 + r) * 72 + cl]) = hv;
            } else {
                size_t base = ((size_t)(row_base + r0 + r) << 6) + cl;
                if constexpr (sizeof(OT) == 2) {
                    ushort4 p;
                    p.x = f2bf(o0); p.y = f2bf(o1); p.z = f2bf(o2); p.w = f2bf(o3);
                    *reinterpret_cast<ushort4*>((ushort_t*)out + base) = p;
                } else {
                    *reinterpret_cast<float4*>((float*)out + base) = make_float4(o0, o1, o2, o3);
                }
            }
        }
    }

    if constexpr (FUSE) {
        __syncthreads();   // all 16 ht rows visible to all waves
        int grp = lane >> 4;   // 0..3
        int lr  = lane & 15;   // 0..15
        f32x4 aq = {0.f, 0.f, 0.f, 0.f};
#pragma unroll
        for (int kc = 0; kc < 2; ++kc) {
            int ko = kc * 32 + grp * 8;
            bf16x8 a = *reinterpret_cast<const bf16x8*>(&ht[lr * 72 + ko]);
            bf16x8 b = *reinterpret_cast<const bf16x8*>(&w2l[(wave * 16 + lr) * 72 + ko]);
            aq = __builtin_amdgcn_mfma_f32_16x16x32_bf16(a, b, aq, 0, 0, 0);
        }
#pragma unroll
        for (int r = 0; r < 4; ++r)
            Snext[((size_t)(row_base + grp * 4 + r) << 6) + wave * 16 + lr] = f2bf(aq[r]);
    }
}

// ---------------- launch ----------------

extern "C" void kernel_launch(void* const* d_in, const int* in_sizes, int n_in,
                              void* d_out, int out_size, void* d_ws, size_t ws_size,
                              hipStream_t stream) {
    const float* features = (const float*)d_in[0];
    const int*   src      = (const int*)d_in[1];
    const int*   dst      = (const int*)d_in[2];
    const float* ew       = (const float*)d_in[3];
    const float* W1       = (const float*)d_in[4];
    const float* b1       = (const float*)d_in[5];
    const float* W2       = (const float*)d_in[6];
    const float* b2       = (const float*)d_in[7];
    const float* W3       = (const float*)d_in[8];
    const float* b3       = (const float*)d_in[9];
    float*       out      = (float*)d_out;

    float*    s_f32  = (float*)d_ws;          // region A: S1, later S3
    ushort_t* sA_bf  = (ushort_t*)d_ws;
    float*    h_f32  = s_f32 + (size_t)NN * 64;  // region B: rec during build, S2 after
    ushort_t* sB_bf  = (ushort_t*)h_f32;
    int*   offsets = (int*)(h_f32 + (size_t)NN * 64);
    int*   gcnt    = offsets + NN + 4;
    int*   bbase   = gcnt + 512;
    int*   wcur    = bbase + 512;
    ushort_t* wt1  = (ushort_t*)(wcur + 512);
    ushort_t* wt2  = wt1 + 64 * 128;
    ushort_t* wt3  = wt2 + 64 * 64;
    int2*  csr     = (int2*)(wt3 + 64 * 64);
    u64*   rec     = (u64*)h_f32;             // dead before spmm1

    (void)hipMemsetAsync(gcnt, 0, NBUCK * sizeof(int), stream);
    wconv_kernel<<<16, 256, 0, stream>>>(W1, W2, W3, wt1, wt2, wt3);
    bucket_hist<<<NHB, 256, 0, stream>>>(dst, gcnt);
    bucket_scan<<<1, 512, 0, stream>>>(gcnt, bbase, wcur, offsets);
    bin_kernel<<<NTILE, 256, 0, stream>>>(src, dst, ew, wcur, rec);
    sort_kernel<<<NBUCK, 256, 0, stream>>>(rec, bbase, offsets, csr);

    int grid_gemm = (NN + 63) / 64;     // 1563
    int grid_spmm = NN / RPB;           // 6250
    size_t shm_plain = ECAP * 8 + 128;
    size_t shm_fused = shm_plain + (16 * 72 + 64 * 72) * 2;

    gemm_mfma<128, float><<<grid_gemm, 256, 0, stream>>>(features, wt1, sA_bf);
    spmm_kernel<true, true, ushort_t><<<grid_spmm, 256, shm_fused, stream>>>(
        csr, offsets, sA_bf, b1, (ushort_t*)nullptr, wt2, sB_bf);
    spmm_kernel<true, true, ushort_t><<<grid_spmm, 256, shm_fused, stream>>>(
        csr, offsets, sB_bf, b2, (ushort_t*)nullptr, wt3, sA_bf);
    spmm_kernel<false, false, float><<<grid_spmm, 256, shm_plain, stream>>>(
        csr, offsets, sA_bf, b3, out, (const ushort_t*)nullptr, (ushort_t*)nullptr);
}